// Round 12
// baseline (95.503 us; speedup 1.0000x reference)
//
#include <hip/hip_runtime.h>
#include <hip/hip_bf16.h>

#define NR 4096

typedef float f32x4 __attribute__((ext_vector_type(4)));
typedef __bf16 bf16x8 __attribute__((ext_vector_type(8)));

typedef __attribute__((address_space(1))) unsigned int u32_g;
typedef __attribute__((address_space(3))) unsigned int u32_l;

__device__ __forceinline__ void gl_lds16(const void* g, void* l) {
  __builtin_amdgcn_global_load_lds((const u32_g*)g, (u32_l*)l, 16, 0, 0);
}

// =====================================================================
// Staged operand layout (bf16): logical Z[rows][K], row-blocks RB of 256,
// K-tiles T of 64:  chunk(row,k) at
//   off = ((RB*KT + T)*2 + s)*16384 + g*4096 + (row&255)*16 + e*2
// B cols expert-interleaved: p = (o>>5)*256+((o>>3)&3)*64+(e>>1)*16+(o&7)*2+(e&1)
//   => in-tile: e = fn*2+(l15&1), o = by*32 + wc*8 + (l15>>1)
// =====================================================================

// ---- 256-thread weight tile stage ----
__device__ void wtile256(const float* __restrict__ w, __hip_bfloat16* __restrict__ out,
                         int Kin, int KT, int Oin, int oblk, int u, char* LDS)
{
  int kt = u % KT;
  int yy = u / KT;
  int e = yy / oblk;
  int o0 = (yy - e * oblk) << 6;
  int k0 = kt << 6;
  float* t = (float*)LDS;  // [64][65]
  int tid = threadIdx.x;
  int tx = tid & 63, ty = tid >> 6;  // 64 x 4
#pragma unroll
  for (int i = 0; i < 16; ++i) {
    int k = k0 + ty + i * 4;
    int o = o0 + tx;
    float v = (k < Kin && o < Oin) ? w[((size_t)e * Kin + k) * Oin + o] : 0.f;
    t[(ty + i * 4) * 65 + tx] = v;
  }
  __syncthreads();
#pragma unroll
  for (int it = 0; it < 2; ++it) {
    int c = it * 256 + tid;
    int j = c & 63, sg = c >> 6;
    bf16x8 v;
#pragma unroll
    for (int e8 = 0; e8 < 8; ++e8) v[e8] = (__bf16)t[(sg * 8 + e8) * 65 + j];
    int o = o0 + j;
    int p = ((o >> 5) << 8) + (((o >> 3) & 3) << 6) + ((e >> 1) << 4) + ((o & 7) << 1) + (e & 1);
    size_t off = (((size_t)(p >> 8) * KT + kt) * 2 + (sg >> 2)) * 16384
               + (size_t)(sg & 3) * 4096 + (size_t)(p & 255) * 16;
    *(bf16x8*)((char*)out + off) = v;
  }
}

// ---- 512-thread weight tile stage (R4-verified; rides inside gemm0) ----
__device__ void wtile512(const float* __restrict__ w, __hip_bfloat16* __restrict__ out,
                         int Kin, int KT, int Oin, int oblk, int u, char* LDS)
{
  int kt = u % KT;
  int yy = u / KT;
  int e = yy / oblk;
  int o0 = (yy - e * oblk) << 6;
  int k0 = kt << 6;
  float* t = (float*)LDS;  // [64][65]
  int tid = threadIdx.x;
  int tx = tid & 63, ty = tid >> 6;  // 64 x 8
#pragma unroll
  for (int i = 0; i < 8; ++i) {
    int k = k0 + ty + i * 8;
    int o = o0 + tx;
    float v = (k < Kin && o < Oin) ? w[((size_t)e * Kin + k) * Oin + o] : 0.f;
    t[(ty + i * 8) * 65 + tx] = v;
  }
  __syncthreads();
  {
    int j = tid & 63, sg = tid >> 6;
    bf16x8 v;
#pragma unroll
    for (int e8 = 0; e8 < 8; ++e8) v[e8] = (__bf16)t[(sg * 8 + e8) * 65 + j];
    int o = o0 + j;
    int p = ((o >> 5) << 8) + (((o >> 3) & 3) << 6) + ((e >> 1) << 4) + ((o & 7) << 1) + (e & 1);
    size_t off = (((size_t)(p >> 8) * KT + kt) * 2 + (sg >> 2)) * 16384
               + (size_t)(sg & 3) * 4096 + (size_t)(p & 255) * 16;
    *(bf16x8*)((char*)out + off) = v;
  }
}

// ---- x0 staging unit: 256 chunks ----
__device__ void x0unit(int u, const float* __restrict__ cond, const float* __restrict__ lat,
                       __hip_bfloat16* __restrict__ out)
{
  int c = u * 256 + threadIdx.x;
  int RB = c / 10240;
  int r1 = c - RB * 10240;
  int T = r1 >> 11, r2 = r1 & 2047;
  int n = RB * 256 + (r2 & 255);
  int k0 = T * 64 + (r2 >> 10) * 32 + ((r2 >> 8) & 3) * 8;
  bf16x8 v;
#pragma unroll
  for (int e = 0; e < 8; ++e) {
    int k = k0 + e;
    float f = (k < 219) ? cond[(size_t)n * 219 + k]
            : (k < 283) ? lat[(size_t)n * 64 + (k - 219)] : 0.f;
    v[e] = (__bf16)f;
  }
  *(bf16x8*)((char*)out + (size_t)c * 16) = v;
}

// ---- x1 latent unit, 512-thr (T=8 of KT=9; R4-verified) ----
__device__ void x1lat512(int u, const float* __restrict__ lat, __hip_bfloat16* __restrict__ out)
{
  int c = u * 512 + threadIdx.x;  // < 32768
  int RB = c >> 11, r2 = c & 2047;
  int n = RB * 256 + (r2 & 255);
  int k0 = (r2 >> 10) * 32 + ((r2 >> 8) & 3) * 8;
  bf16x8 v;
#pragma unroll
  for (int e = 0; e < 8; ++e) v[e] = (__bf16)lat[(size_t)n * 64 + k0 + e];
  size_t off = ((size_t)RB * 9 + 8) * 32768 + (size_t)r2 * 16;
  *(bf16x8*)((char*)out + off) = v;
}

// ---- prepA: ONLY what gemm0 needs — w0 tiles + x0 staging ----
__global__ __launch_bounds__(256) void prepA(
    const float* __restrict__ latent, const float* __restrict__ condition,
    const float* __restrict__ w0,
    __hip_bfloat16* x0s, __hip_bfloat16* w0s)
{
  __shared__ __align__(16) char LDS[64 * 65 * 4];
  int b = blockIdx.x;
  if (b < 320) wtile256(w0, w0s, 283, 5, 512, 8, b, LDS);
  else         x0unit(b - 320, condition, latent, x0s);  // 640 units
}

// ---- gate kernel: LDS-cached weights, 4x4 register-blocked, exact fp32 ----
__global__ __launch_bounds__(256) void gate_k(
    const float* __restrict__ phs, const float* __restrict__ lat,
    const float* __restrict__ gw1, const float* __restrict__ gb1,
    const float* __restrict__ gw2, const float* __restrict__ gb2,
    const float* __restrict__ gw3, const float* __restrict__ gb3,
    float* __restrict__ coeff)
{
  __shared__ __align__(16) float wL[128 * 128];   // 64KB, reused w1 -> w2
  __shared__ __align__(16) float g0T[104 * 36];   // [k][row]
  __shared__ __align__(16) float h1T[128 * 36];
  __shared__ __align__(16) float h2T[128 * 36];
  __shared__ __align__(16) float w3L[128 * 8];
  const int tid = threadIdx.x;
  const int n0 = blockIdx.x * 32;

  for (int i = tid; i < 104 * 32; i += 256) {
    int k = i >> 5, r = i & 31;
    g0T[k * 36 + r] = (k < 40) ? phs[(size_t)(n0 + r) * 40 + k]
                               : lat[(size_t)(n0 + r) * 64 + (k - 40)];
  }
  for (int i = tid; i < 104 * 32; i += 256) ((float4*)wL)[i] = ((const float4*)gw1)[i];
  ((float4*)w3L)[tid] = ((const float4*)gw3)[tid];
  __syncthreads();

  const int ct = tid & 31, rt = tid >> 5;
  const int c0 = ct << 2, r0 = rt << 2;

  // layer 1
  {
    f32x4 a0 = {}, a1 = {}, a2 = {}, a3 = {};
    for (int k = 0; k < 104; ++k) {
      f32x4 g = *(const f32x4*)&g0T[k * 36 + r0];
      f32x4 w = *(const f32x4*)&wL[k * 128 + c0];
      a0 += g * w.x; a1 += g * w.y; a2 += g * w.z; a3 += g * w.w;
    }
    f32x4 bb = *(const f32x4*)&gb1[c0];
    a0 += bb.x; a1 += bb.y; a2 += bb.z; a3 += bb.w;
#pragma unroll
    for (int j = 0; j < 4; ++j) {
      a0[j] = a0[j] > 0.f ? a0[j] : expm1f(a0[j]);
      a1[j] = a1[j] > 0.f ? a1[j] : expm1f(a1[j]);
      a2[j] = a2[j] > 0.f ? a2[j] : expm1f(a2[j]);
      a3[j] = a3[j] > 0.f ? a3[j] : expm1f(a3[j]);
    }
    *(f32x4*)&h1T[(c0 + 0) * 36 + r0] = a0;
    *(f32x4*)&h1T[(c0 + 1) * 36 + r0] = a1;
    *(f32x4*)&h1T[(c0 + 2) * 36 + r0] = a2;
    *(f32x4*)&h1T[(c0 + 3) * 36 + r0] = a3;
  }
  __syncthreads();
  for (int i = tid; i < 128 * 32; i += 256) ((float4*)wL)[i] = ((const float4*)gw2)[i];
  __syncthreads();

  // layer 2
  {
    f32x4 a0 = {}, a1 = {}, a2 = {}, a3 = {};
    for (int k = 0; k < 128; ++k) {
      f32x4 g = *(const f32x4*)&h1T[k * 36 + r0];
      f32x4 w = *(const f32x4*)&wL[k * 128 + c0];
      a0 += g * w.x; a1 += g * w.y; a2 += g * w.z; a3 += g * w.w;
    }
    f32x4 bb = *(const f32x4*)&gb2[c0];
    a0 += bb.x; a1 += bb.y; a2 += bb.z; a3 += bb.w;
#pragma unroll
    for (int j = 0; j < 4; ++j) {
      a0[j] = a0[j] > 0.f ? a0[j] : expm1f(a0[j]);
      a1[j] = a1[j] > 0.f ? a1[j] : expm1f(a1[j]);
      a2[j] = a2[j] > 0.f ? a2[j] : expm1f(a2[j]);
      a3[j] = a3[j] > 0.f ? a3[j] : expm1f(a3[j]);
    }
    *(f32x4*)&h2T[(c0 + 0) * 36 + r0] = a0;
    *(f32x4*)&h2T[(c0 + 1) * 36 + r0] = a1;
    *(f32x4*)&h2T[(c0 + 2) * 36 + r0] = a2;
    *(f32x4*)&h2T[(c0 + 3) * 36 + r0] = a3;
  }
  __syncthreads();

  // layer 3 + softmax
  {
    int row = tid >> 3, e = tid & 7;
    float acc = 0.f;
    for (int k = 0; k < 128; ++k) acc += h2T[k * 36 + row] * w3L[k * 8 + e];
    float lgt = acc + gb3[e];
    float m = lgt;
    m = fmaxf(m, __shfl_xor(m, 1));
    m = fmaxf(m, __shfl_xor(m, 2));
    m = fmaxf(m, __shfl_xor(m, 4));
    float ex = expf(lgt - m);
    float s = ex;
    s += __shfl_xor(s, 1);
    s += __shfl_xor(s, 2);
    s += __shfl_xor(s, 4);
    coeff[(size_t)(n0 + row) * 8 + e] = ex / s;
  }
}

// =====================================================================
// GEMM: 128x256 tile, 48KB LDS single-buffer, 2 blocks/CU (R11-verified).
// RIDE=true (gemm0): blocks >= NGEMM stage next-layer weights + x1 latent,
// overlapping with the GEMM under 2/CU co-residency.
// =====================================================================
template <int KT, int KTD, int MODE, bool RIDE, int NGEMM>
__global__ __launch_bounds__(512, 4) void gemm_k(
    const __hip_bfloat16* __restrict__ Ap, const __hip_bfloat16* __restrict__ Bp,
    const float* __restrict__ coeff, const float* __restrict__ bias,
    __hip_bfloat16* __restrict__ dstS, float* __restrict__ dstF,
    const float* __restrict__ latent,
    const float* __restrict__ w1g, const float* __restrict__ w2g,
    __hip_bfloat16* __restrict__ w1sd, __hip_bfloat16* __restrict__ w2sd)
{
  __shared__ __align__(16) char lds[49152];   // A 16KB | B 32KB; epilogue overlays
  const int bid = blockIdx.x;
  if (RIDE && bid >= NGEMM) {
    int u = bid - NGEMM;
    if (u < 576)      wtile512(w1g, w1sd, 576, 9, 512, 8, u, lds);
    else if (u < 768) wtile512(w2g, w2sd, 512, 8, 171, 3, u - 576, lds);
    else              x1lat512(u - 768, latent, dstS);  // dstS == x1s for gemm0
    return;
  }
  const int bx = bid & 31;          // M-tile (128 rows)
  const int by = bid >> 5;          // N-tile (256 cols)
  const int tid = threadIdx.x;
  const int lane = tid & 63;
  const int wid = tid >> 6;
  const int wr = wid >> 2, wc = wid & 3;
  const int l15 = lane & 15, lg = lane >> 4;
  const int aHalf = (bx & 1) * 2048;

  const char* aG = (const char*)Ap + (size_t)(bx >> 1) * KT * 32768;
  const char* bG = (const char*)Bp + (size_t)by * KT * 32768;

#define STAGE(T)                                                             \
  {                                                                          \
    const char* gA_ = aG + (size_t)(T) * 32768;                              \
    const char* gB_ = bG + (size_t)(T) * 32768;                              \
    _Pragma("unroll") for (int i = 0; i < 2; ++i) {                          \
      int c = i * 512 + tid;                                                 \
      gl_lds16(gA_ + (c >> 9) * 16384 + ((c >> 7) & 3) * 4096 + aHalf        \
                   + (c & 127) * 16,                                         \
               lds + c * 16);                                                \
    }                                                                        \
    _Pragma("unroll") for (int i = 0; i < 4; ++i) {                          \
      int c = i * 512 + tid;                                                 \
      gl_lds16(gB_ + c * 16, lds + 16384 + c * 16);                          \
    }                                                                        \
  }

  f32x4 acc[4][4] = {};

  STAGE(0);
  asm volatile("s_waitcnt vmcnt(0)" ::: "memory");
  __builtin_amdgcn_s_barrier();

#pragma unroll 1
  for (int t = 0; t < KT; ++t) {
#pragma unroll
    for (int s = 0; s < 2; ++s) {
      bf16x8 a[4], b[4];
#pragma unroll
      for (int fm = 0; fm < 4; ++fm)
        a[fm] = *(const bf16x8*)(lds + s * 8192 + lg * 2048
                                 + ((wr << 6) + fm * 16 + l15) * 16);
#pragma unroll
      for (int nf = 0; nf < 4; ++nf)
        b[nf] = *(const bf16x8*)(lds + 16384 + s * 16384 + lg * 4096
                                 + (wc << 10) + nf * 256 + l15 * 16);
#pragma unroll
      for (int fm = 0; fm < 4; ++fm)
#pragma unroll
        for (int nf = 0; nf < 4; ++nf)
          acc[fm][nf] = __builtin_amdgcn_mfma_f32_16x16x32_bf16(a[fm], b[nf], acc[fm][nf], 0, 0, 0);
    }
    if (t + 1 < KT) {
      __builtin_amdgcn_s_barrier();
      STAGE(t + 1);
      asm volatile("s_waitcnt vmcnt(0)" ::: "memory");
      __builtin_amdgcn_s_barrier();
    }
  }
#undef STAGE
  __syncthreads();  // lds reuse boundary

  // ---- fused expert-blend epilogue (coeff transposed [8][132]: conflict-free) ----
  float* cl2 = (float*)lds;                  // 8 x 132 f32
  float* tb  = (float*)(lds + 4352);         // [128][33] f32 (MODE 0)
  {
#pragma unroll
    for (int i = 0; i < 2; ++i) {
      int idx = i * 512 + tid;
      int e = idx & 7, n = idx >> 3;
      cl2[e * 132 + n] = coeff[((size_t)bx * 128 + n) * 8 + e];
    }
  }
  __syncthreads();
  const int e0 = lane & 1;
  const int o_loc = (wc << 3) + (l15 >> 1);

  if (MODE == 0) {
    float bb[4];
#pragma unroll
    for (int fn = 0; fn < 4; ++fn) bb[fn] = bias[(fn * 2 + e0) * 512 + by * 32 + o_loc];
#pragma unroll
    for (int fm = 0; fm < 4; ++fm) {
#pragma unroll
      for (int r = 0; r < 4; ++r) {
        int n_loc = (wr << 6) + fm * 16 + (lg << 2) + r;
        float s = 0.f;
#pragma unroll
        for (int fn = 0; fn < 4; ++fn)
          s += cl2[(fn * 2 + e0) * 132 + n_loc] * (acc[fm][fn][r] + bb[fn]);
        s += __shfl_xor(s, 1);
        s = s > 0.f ? s : expm1f(s);
        if ((lane & 1) == (fm & 1)) tb[n_loc * 33 + o_loc] = s;
      }
    }
    __syncthreads();
    {
      int n_loc = tid & 127, c = tid >> 7;
      const float* p = &tb[n_loc * 33 + c * 8];
      bf16x8 v;
#pragma unroll
      for (int j = 0; j < 8; ++j) v[j] = (__bf16)p[j];
      size_t off = (((size_t)(bx >> 1) * KTD + (by >> 1)) * 2 + (by & 1)) * 16384
                 + (size_t)c * 4096 + (size_t)((bx & 1) * 128 + n_loc) * 16;
      *(bf16x8*)((char*)dstS + off) = v;
    }
  } else {
    const int o_g = by * 32 + o_loc;
    if (o_g < 171) {
      float bb[4];
#pragma unroll
      for (int fn = 0; fn < 4; ++fn) bb[fn] = bias[(fn * 2 + e0) * 171 + o_g];
#pragma unroll
      for (int fm = 0; fm < 4; ++fm) {
#pragma unroll
        for (int r = 0; r < 4; ++r) {
          int n_loc = (wr << 6) + fm * 16 + (lg << 2) + r;
          float s = 0.f;
#pragma unroll
          for (int fn = 0; fn < 4; ++fn)
            s += cl2[(fn * 2 + e0) * 132 + n_loc] * (acc[fm][fn][r] + bb[fn]);
          s += __shfl_xor(s, 1);
          if ((lane & 1) == (fm & 1))
            dstF[(size_t)(bx * 128 + n_loc) * 171 + o_g] = s;
        }
      }
    }
  }
}

// ---------------- launch ----------------
extern "C" void kernel_launch(void* const* d_in, const int* in_sizes, int n_in,
                              void* d_out, int out_size, void* d_ws, size_t ws_size,
                              hipStream_t stream)
{
  const float* latent    = (const float*)d_in[0];
  const float* condition = (const float*)d_in[1];
  const float* phase     = (const float*)d_in[2];
  const float* gw1 = (const float*)d_in[3];
  const float* gb1 = (const float*)d_in[4];
  const float* gw2 = (const float*)d_in[5];
  const float* gb2 = (const float*)d_in[6];
  const float* gw3 = (const float*)d_in[7];
  const float* gb3 = (const float*)d_in[8];
  const float* w0  = (const float*)d_in[9];
  const float* b0  = (const float*)d_in[10];
  const float* w1  = (const float*)d_in[11];
  const float* b1  = (const float*)d_in[12];
  const float* w2  = (const float*)d_in[13];
  const float* b2  = (const float*)d_in[14];

  float* out   = (float*)d_out;
  float* coeff = out + (size_t)NR * 171;

  char* ws = (char*)d_ws;
  __hip_bfloat16* x0s = (__hip_bfloat16*)ws; ws += (size_t)16 * 5 * 32768;
  __hip_bfloat16* x1s = (__hip_bfloat16*)ws; ws += (size_t)16 * 9 * 32768;
  __hip_bfloat16* x2s = (__hip_bfloat16*)ws; ws += (size_t)16 * 8 * 32768;
  __hip_bfloat16* w0s = (__hip_bfloat16*)ws; ws += (size_t)16 * 5 * 32768;
  __hip_bfloat16* w1s = (__hip_bfloat16*)ws; ws += (size_t)16 * 9 * 32768;
  __hip_bfloat16* w2s = (__hip_bfloat16*)ws; ws += (size_t)6 * 8 * 32768;

  // K1: gate (exact fp32)
  gate_k<<<128, 256, 0, stream>>>(phase, latent, gw1, gb1, gw2, gb2, gw3, gb3, coeff);

  // K2: prepA — only gemm0's inputs (w0 tiles 320 + x0 units 640)
  prepA<<<960, 256, 0, stream>>>(latent, condition, w0, x0s, w0s);

  // K3: gemm0 (512 blocks) + ride-along staging of w1s/w2s/x1lat (832 blocks)
  gemm_k<5, 9, 0, true, 512><<<1344, 512, 0, stream>>>(
      x0s, w0s, coeff, b0, x1s, nullptr, latent, w1, w2, w1s, w2s);

  // K4: gemm1 (pure)
  gemm_k<9, 8, 0, false, 512><<<512, 512, 0, stream>>>(
      x1s, w1s, coeff, b1, x2s, nullptr, nullptr, nullptr, nullptr, nullptr, nullptr);

  // K5: gemm2 -> out fp32
  gemm_k<8, 0, 1, false, 192><<<192, 512, 0, stream>>>(
      x2s, w2s, coeff, b2, nullptr, out, nullptr, nullptr, nullptr, nullptr, nullptr);
}

// Round 13
// 92.326 us; speedup vs baseline: 1.0344x; 1.0344x over previous
//
#include <hip/hip_runtime.h>
#include <hip/hip_bf16.h>

#define NR 4096

typedef float f32x4 __attribute__((ext_vector_type(4)));
typedef __bf16 bf16x8 __attribute__((ext_vector_type(8)));

typedef __attribute__((address_space(1))) unsigned int u32_g;
typedef __attribute__((address_space(3))) unsigned int u32_l;

__device__ __forceinline__ void gl_lds16(const void* g, void* l) {
  __builtin_amdgcn_global_load_lds((const u32_g*)g, (u32_l*)l, 16, 0, 0);
}

// =====================================================================
// Staged operand layout (bf16): logical Z[rows][K], row-blocks RB of 256,
// K-tiles T of 64:  chunk(row,k) at
//   off = ((RB*KT + T)*2 + s)*16384 + g*4096 + (row&255)*16 + e*2
// B cols expert-interleaved: p = (o>>5)*256+((o>>3)&3)*64+(e>>1)*16+(o&7)*2+(e&1)
//   => in-tile: e = fn*2+(l15&1), o = by*32 + wc*8 + (l15>>1)
// =====================================================================

// ---- 256-thread weight tile stage ----
__device__ void wtile256(const float* __restrict__ w, __hip_bfloat16* __restrict__ out,
                         int Kin, int KT, int Oin, int oblk, int u, char* LDS)
{
  int kt = u % KT;
  int yy = u / KT;
  int e = yy / oblk;
  int o0 = (yy - e * oblk) << 6;
  int k0 = kt << 6;
  float* t = (float*)LDS;  // [64][65]
  int tid = threadIdx.x;
  int tx = tid & 63, ty = tid >> 6;  // 64 x 4
#pragma unroll
  for (int i = 0; i < 16; ++i) {
    int k = k0 + ty + i * 4;
    int o = o0 + tx;
    float v = (k < Kin && o < Oin) ? w[((size_t)e * Kin + k) * Oin + o] : 0.f;
    t[(ty + i * 4) * 65 + tx] = v;
  }
  __syncthreads();
#pragma unroll
  for (int it = 0; it < 2; ++it) {
    int c = it * 256 + tid;
    int j = c & 63, sg = c >> 6;
    bf16x8 v;
#pragma unroll
    for (int e8 = 0; e8 < 8; ++e8) v[e8] = (__bf16)t[(sg * 8 + e8) * 65 + j];
    int o = o0 + j;
    int p = ((o >> 5) << 8) + (((o >> 3) & 3) << 6) + ((e >> 1) << 4) + ((o & 7) << 1) + (e & 1);
    size_t off = (((size_t)(p >> 8) * KT + kt) * 2 + (sg >> 2)) * 16384
               + (size_t)(sg & 3) * 4096 + (size_t)(p & 255) * 16;
    *(bf16x8*)((char*)out + off) = v;
  }
}

// ---- x0 staging unit: 256 chunks ----
__device__ void x0unit(int u, const float* __restrict__ cond, const float* __restrict__ lat,
                       __hip_bfloat16* __restrict__ out)
{
  int c = u * 256 + threadIdx.x;
  int RB = c / 10240;
  int r1 = c - RB * 10240;
  int T = r1 >> 11, r2 = r1 & 2047;
  int n = RB * 256 + (r2 & 255);
  int k0 = T * 64 + (r2 >> 10) * 32 + ((r2 >> 8) & 3) * 8;
  bf16x8 v;
#pragma unroll
  for (int e = 0; e < 8; ++e) {
    int k = k0 + e;
    float f = (k < 219) ? cond[(size_t)n * 219 + k]
            : (k < 283) ? lat[(size_t)n * 64 + (k - 219)] : 0.f;
    v[e] = (__bf16)f;
  }
  *(bf16x8*)((char*)out + (size_t)c * 16) = v;
}

// ---- x1 latent unit (T=8 of KT=9): 256 chunks ----
__device__ void x1lat(int u, const float* __restrict__ lat, __hip_bfloat16* __restrict__ out)
{
  int c = u * 256 + threadIdx.x;  // 0..32767
  int RB = c >> 11, r2 = c & 2047;
  int n = RB * 256 + (r2 & 255);
  int k0 = (r2 >> 10) * 32 + ((r2 >> 8) & 3) * 8;
  bf16x8 v;
#pragma unroll
  for (int e = 0; e < 8; ++e) v[e] = (__bf16)lat[(size_t)n * 64 + k0 + e];
  size_t off = ((size_t)RB * 9 + 8) * 32768 + (size_t)r2 * 16;
  *(bf16x8*)((char*)out + off) = v;
}

// ---- prepS: ALL staging, one wide kernel, every block independent ----
__global__ __launch_bounds__(256) void prepS(
    const float* __restrict__ latent, const float* __restrict__ condition,
    const float* __restrict__ w0, const float* __restrict__ w1, const float* __restrict__ w2,
    __hip_bfloat16* x0s, __hip_bfloat16* x1s,
    __hip_bfloat16* w0s, __hip_bfloat16* w1s, __hip_bfloat16* w2s)
{
  __shared__ __align__(16) char LDS[64 * 65 * 4];
  int b = blockIdx.x;
  if (b < 320)       wtile256(w0, w0s, 283, 5, 512, 8, b, LDS);
  else if (b < 896)  wtile256(w1, w1s, 576, 9, 512, 8, b - 320, LDS);
  else if (b < 1088) wtile256(w2, w2s, 512, 8, 171, 3, b - 896, LDS);
  else if (b < 1152) {
    int u0 = b - 1088;
    x1lat(u0, latent, x1s);
    x1lat(u0 + 64, latent, x1s);
  } else {
    x0unit(b - 1152, condition, latent, x0s);  // 640 units
  }
}

// ---- gate kernel: LDS-cached weights, 4x4 register-blocked, exact fp32 ----
__global__ __launch_bounds__(256) void gate_k(
    const float* __restrict__ phs, const float* __restrict__ lat,
    const float* __restrict__ gw1, const float* __restrict__ gb1,
    const float* __restrict__ gw2, const float* __restrict__ gb2,
    const float* __restrict__ gw3, const float* __restrict__ gb3,
    float* __restrict__ coeff)
{
  __shared__ __align__(16) float wL[128 * 128];   // 64KB, reused w1 -> w2
  __shared__ __align__(16) float g0T[104 * 36];   // [k][row]
  __shared__ __align__(16) float h1T[128 * 36];
  __shared__ __align__(16) float h2T[128 * 36];
  __shared__ __align__(16) float w3L[128 * 8];
  const int tid = threadIdx.x;
  const int n0 = blockIdx.x * 32;

  for (int i = tid; i < 104 * 32; i += 256) {
    int k = i >> 5, r = i & 31;
    g0T[k * 36 + r] = (k < 40) ? phs[(size_t)(n0 + r) * 40 + k]
                               : lat[(size_t)(n0 + r) * 64 + (k - 40)];
  }
  for (int i = tid; i < 104 * 32; i += 256) ((float4*)wL)[i] = ((const float4*)gw1)[i];
  ((float4*)w3L)[tid] = ((const float4*)gw3)[tid];
  __syncthreads();

  const int ct = tid & 31, rt = tid >> 5;
  const int c0 = ct << 2, r0 = rt << 2;

  // layer 1
  {
    f32x4 a0 = {}, a1 = {}, a2 = {}, a3 = {};
    for (int k = 0; k < 104; ++k) {
      f32x4 g = *(const f32x4*)&g0T[k * 36 + r0];
      f32x4 w = *(const f32x4*)&wL[k * 128 + c0];
      a0 += g * w.x; a1 += g * w.y; a2 += g * w.z; a3 += g * w.w;
    }
    f32x4 bb = *(const f32x4*)&gb1[c0];
    a0 += bb.x; a1 += bb.y; a2 += bb.z; a3 += bb.w;
#pragma unroll
    for (int j = 0; j < 4; ++j) {
      a0[j] = a0[j] > 0.f ? a0[j] : expm1f(a0[j]);
      a1[j] = a1[j] > 0.f ? a1[j] : expm1f(a1[j]);
      a2[j] = a2[j] > 0.f ? a2[j] : expm1f(a2[j]);
      a3[j] = a3[j] > 0.f ? a3[j] : expm1f(a3[j]);
    }
    *(f32x4*)&h1T[(c0 + 0) * 36 + r0] = a0;
    *(f32x4*)&h1T[(c0 + 1) * 36 + r0] = a1;
    *(f32x4*)&h1T[(c0 + 2) * 36 + r0] = a2;
    *(f32x4*)&h1T[(c0 + 3) * 36 + r0] = a3;
  }
  __syncthreads();
  for (int i = tid; i < 128 * 32; i += 256) ((float4*)wL)[i] = ((const float4*)gw2)[i];
  __syncthreads();

  // layer 2
  {
    f32x4 a0 = {}, a1 = {}, a2 = {}, a3 = {};
    for (int k = 0; k < 128; ++k) {
      f32x4 g = *(const f32x4*)&h1T[k * 36 + r0];
      f32x4 w = *(const f32x4*)&wL[k * 128 + c0];
      a0 += g * w.x; a1 += g * w.y; a2 += g * w.z; a3 += g * w.w;
    }
    f32x4 bb = *(const f32x4*)&gb2[c0];
    a0 += bb.x; a1 += bb.y; a2 += bb.z; a3 += bb.w;
#pragma unroll
    for (int j = 0; j < 4; ++j) {
      a0[j] = a0[j] > 0.f ? a0[j] : expm1f(a0[j]);
      a1[j] = a1[j] > 0.f ? a1[j] : expm1f(a1[j]);
      a2[j] = a2[j] > 0.f ? a2[j] : expm1f(a2[j]);
      a3[j] = a3[j] > 0.f ? a3[j] : expm1f(a3[j]);
    }
    *(f32x4*)&h2T[(c0 + 0) * 36 + r0] = a0;
    *(f32x4*)&h2T[(c0 + 1) * 36 + r0] = a1;
    *(f32x4*)&h2T[(c0 + 2) * 36 + r0] = a2;
    *(f32x4*)&h2T[(c0 + 3) * 36 + r0] = a3;
  }
  __syncthreads();

  // layer 3 + softmax
  {
    int row = tid >> 3, e = tid & 7;
    float acc = 0.f;
    for (int k = 0; k < 128; ++k) acc += h2T[k * 36 + row] * w3L[k * 8 + e];
    float lgt = acc + gb3[e];
    float m = lgt;
    m = fmaxf(m, __shfl_xor(m, 1));
    m = fmaxf(m, __shfl_xor(m, 2));
    m = fmaxf(m, __shfl_xor(m, 4));
    float ex = expf(lgt - m);
    float s = ex;
    s += __shfl_xor(s, 1);
    s += __shfl_xor(s, 2);
    s += __shfl_xor(s, 4);
    coeff[(size_t)(n0 + row) * 8 + e] = ex / s;
  }
}

// =====================================================================
// GEMM: 128x256 tile, 48KB LDS single-buffer, 2 blocks/CU (R11-verified),
// now with rectangular per-XCD tile mapping: XCD x gets an 8bx-by-BYPG-by
// rectangle => per-XCD L2 footprint 3.5MB (gemm1) < 4MB L2.
// MODE 0 -> staged bf16 next-layer activations; MODE 1 -> fp32 final out.
// =====================================================================
template <int KT, int KTD, int MODE, int BYPG>
__global__ __launch_bounds__(512, 4) void gemm_k(
    const __hip_bfloat16* __restrict__ Ap, const __hip_bfloat16* __restrict__ Bp,
    const float* __restrict__ coeff, const float* __restrict__ bias,
    __hip_bfloat16* __restrict__ dstS, float* __restrict__ dstF)
{
  __shared__ __align__(16) char lds[49152];   // A 16KB | B 32KB; epilogue overlays
  const int bid = blockIdx.x;
  // rectangular XCD swizzle (bijective): xcd=bid&7 under round-robin dispatch
  const int xcd = bid & 7, r = bid >> 3;
  const int bx = ((xcd & 3) << 3) + (r & 7);          // 8 consecutive bx per XCD
  const int by = (xcd >> 2) * BYPG + (r >> 3);        // BYPG consecutive by per XCD
  const int tid = threadIdx.x;
  const int lane = tid & 63;
  const int wid = tid >> 6;
  const int wr = wid >> 2, wc = wid & 3;
  const int l15 = lane & 15, lg = lane >> 4;
  const int aHalf = (bx & 1) * 2048;

  const char* aG = (const char*)Ap + (size_t)(bx >> 1) * KT * 32768;
  const char* bG = (const char*)Bp + (size_t)by * KT * 32768;

#define STAGE(T)                                                             \
  {                                                                          \
    const char* gA_ = aG + (size_t)(T) * 32768;                              \
    const char* gB_ = bG + (size_t)(T) * 32768;                              \
    _Pragma("unroll") for (int i = 0; i < 2; ++i) {                          \
      int c = i * 512 + tid;                                                 \
      gl_lds16(gA_ + (c >> 9) * 16384 + ((c >> 7) & 3) * 4096 + aHalf        \
                   + (c & 127) * 16,                                         \
               lds + c * 16);                                                \
    }                                                                        \
    _Pragma("unroll") for (int i = 0; i < 4; ++i) {                          \
      int c = i * 512 + tid;                                                 \
      gl_lds16(gB_ + c * 16, lds + 16384 + c * 16);                          \
    }                                                                        \
  }

  f32x4 acc[4][4] = {};

  STAGE(0);
  asm volatile("s_waitcnt vmcnt(0)" ::: "memory");
  __builtin_amdgcn_s_barrier();

#pragma unroll 1
  for (int t = 0; t < KT; ++t) {
#pragma unroll
    for (int s = 0; s < 2; ++s) {
      bf16x8 a[4], b[4];
#pragma unroll
      for (int fm = 0; fm < 4; ++fm)
        a[fm] = *(const bf16x8*)(lds + s * 8192 + lg * 2048
                                 + ((wr << 6) + fm * 16 + l15) * 16);
#pragma unroll
      for (int nf = 0; nf < 4; ++nf)
        b[nf] = *(const bf16x8*)(lds + 16384 + s * 16384 + lg * 4096
                                 + (wc << 10) + nf * 256 + l15 * 16);
#pragma unroll
      for (int fm = 0; fm < 4; ++fm)
#pragma unroll
        for (int nf = 0; nf < 4; ++nf)
          acc[fm][nf] = __builtin_amdgcn_mfma_f32_16x16x32_bf16(a[fm], b[nf], acc[fm][nf], 0, 0, 0);
    }
    if (t + 1 < KT) {
      __builtin_amdgcn_s_barrier();
      STAGE(t + 1);
      asm volatile("s_waitcnt vmcnt(0)" ::: "memory");
      __builtin_amdgcn_s_barrier();
    }
  }
#undef STAGE
  __syncthreads();  // lds reuse boundary

  // ---- fused expert-blend epilogue (coeff transposed [8][132]: conflict-free) ----
  float* cl2 = (float*)lds;                  // 8 x 132 f32
  float* tb  = (float*)(lds + 4352);         // [128][33] f32 (MODE 0)
  {
#pragma unroll
    for (int i = 0; i < 2; ++i) {
      int idx = i * 512 + tid;
      int e = idx & 7, n = idx >> 3;
      cl2[e * 132 + n] = coeff[((size_t)bx * 128 + n) * 8 + e];
    }
  }
  __syncthreads();
  const int e0 = lane & 1;
  const int o_loc = (wc << 3) + (l15 >> 1);

  if (MODE == 0) {
    float bb[4];
#pragma unroll
    for (int fn = 0; fn < 4; ++fn) bb[fn] = bias[(fn * 2 + e0) * 512 + by * 32 + o_loc];
#pragma unroll
    for (int fm = 0; fm < 4; ++fm) {
#pragma unroll
      for (int r2 = 0; r2 < 4; ++r2) {
        int n_loc = (wr << 6) + fm * 16 + (lg << 2) + r2;
        float s = 0.f;
#pragma unroll
        for (int fn = 0; fn < 4; ++fn)
          s += cl2[(fn * 2 + e0) * 132 + n_loc] * (acc[fm][fn][r2] + bb[fn]);
        s += __shfl_xor(s, 1);
        s = s > 0.f ? s : expm1f(s);
        if ((lane & 1) == (fm & 1)) tb[n_loc * 33 + o_loc] = s;
      }
    }
    __syncthreads();
    {
      int n_loc = tid & 127, c = tid >> 7;
      const float* p = &tb[n_loc * 33 + c * 8];
      bf16x8 v;
#pragma unroll
      for (int j = 0; j < 8; ++j) v[j] = (__bf16)p[j];
      size_t off = (((size_t)(bx >> 1) * KTD + (by >> 1)) * 2 + (by & 1)) * 16384
                 + (size_t)c * 4096 + (size_t)((bx & 1) * 128 + n_loc) * 16;
      *(bf16x8*)((char*)dstS + off) = v;
    }
  } else {
    const int o_g = by * 32 + o_loc;
    if (o_g < 171) {
      float bb[4];
#pragma unroll
      for (int fn = 0; fn < 4; ++fn) bb[fn] = bias[(fn * 2 + e0) * 171 + o_g];
#pragma unroll
      for (int fm = 0; fm < 4; ++fm) {
#pragma unroll
        for (int r2 = 0; r2 < 4; ++r2) {
          int n_loc = (wr << 6) + fm * 16 + (lg << 2) + r2;
          float s = 0.f;
#pragma unroll
          for (int fn = 0; fn < 4; ++fn)
            s += cl2[(fn * 2 + e0) * 132 + n_loc] * (acc[fm][fn][r2] + bb[fn]);
          s += __shfl_xor(s, 1);
          if ((lane & 1) == (fm & 1))
            dstF[(size_t)(bx * 128 + n_loc) * 171 + o_g] = s;
        }
      }
    }
  }
}

// ---------------- launch ----------------
extern "C" void kernel_launch(void* const* d_in, const int* in_sizes, int n_in,
                              void* d_out, int out_size, void* d_ws, size_t ws_size,
                              hipStream_t stream)
{
  const float* latent    = (const float*)d_in[0];
  const float* condition = (const float*)d_in[1];
  const float* phase     = (const float*)d_in[2];
  const float* gw1 = (const float*)d_in[3];
  const float* gb1 = (const float*)d_in[4];
  const float* gw2 = (const float*)d_in[5];
  const float* gb2 = (const float*)d_in[6];
  const float* gw3 = (const float*)d_in[7];
  const float* gb3 = (const float*)d_in[8];
  const float* w0  = (const float*)d_in[9];
  const float* b0  = (const float*)d_in[10];
  const float* w1  = (const float*)d_in[11];
  const float* b1  = (const float*)d_in[12];
  const float* w2  = (const float*)d_in[13];
  const float* b2  = (const float*)d_in[14];

  float* out   = (float*)d_out;
  float* coeff = out + (size_t)NR * 171;

  char* ws = (char*)d_ws;
  __hip_bfloat16* x0s = (__hip_bfloat16*)ws; ws += (size_t)16 * 5 * 32768;
  __hip_bfloat16* x1s = (__hip_bfloat16*)ws; ws += (size_t)16 * 9 * 32768;
  __hip_bfloat16* x2s = (__hip_bfloat16*)ws; ws += (size_t)16 * 8 * 32768;
  __hip_bfloat16* w0s = (__hip_bfloat16*)ws; ws += (size_t)16 * 5 * 32768;
  __hip_bfloat16* w1s = (__hip_bfloat16*)ws; ws += (size_t)16 * 9 * 32768;
  __hip_bfloat16* w2s = (__hip_bfloat16*)ws; ws += (size_t)6 * 8 * 32768;

  // K1: gate (exact fp32, LDS-cached weights)
  gate_k<<<128, 256, 0, stream>>>(phase, latent, gw1, gb1, gw2, gb2, gw3, gb3, coeff);

  // K2: all staging in parallel (R11 config restored)
  prepS<<<1792, 256, 0, stream>>>(latent, condition, w0, w1, w2,
                                  x0s, x1s, w0s, w1s, w2s);

  // K3-K5: 128x256-tile fused GEMMs, rectangular XCD-L2 tile mapping
  gemm_k<5, 9, 0, 8><<<512, 512, 0, stream>>>(x0s, w0s, coeff, b0, x1s, nullptr);
  gemm_k<9, 8, 0, 8><<<512, 512, 0, stream>>>(x1s, w1s, coeff, b1, x2s, nullptr);
  gemm_k<8, 0, 1, 3><<<192, 512, 0, stream>>>(x2s, w2s, coeff, b2, nullptr, out);
}

// Round 14
// 85.087 us; speedup vs baseline: 1.1224x; 1.0851x over previous
//
#include <hip/hip_runtime.h>
#include <hip/hip_bf16.h>

#define NR 4096

typedef float f32x4 __attribute__((ext_vector_type(4)));
typedef __bf16 bf16x8 __attribute__((ext_vector_type(8)));

typedef __attribute__((address_space(1))) unsigned int u32_g;
typedef __attribute__((address_space(3))) unsigned int u32_l;

__device__ __forceinline__ void gl_lds16(const void* g, void* l) {
  __builtin_amdgcn_global_load_lds((const u32_g*)g, (u32_l*)l, 16, 0, 0);
}

// =====================================================================
// Staged operand layout (bf16): logical Z[rows][K], row-blocks RB of 256,
// K-tiles T of 64:  chunk(row,k) at
//   off = ((RB*KT + T)*2 + s)*16384 + g*4096 + (row&255)*16 + e*2
// B cols expert-interleaved: p = (o>>5)*256+((o>>3)&3)*64+(e>>1)*16+(o&7)*2+(e&1)
//   => in-tile: e = fn*2+(l15&1), o = by*32 + wc*8 + (l15>>1)
// =====================================================================

// ---- 256-thread weight tile stage ----
__device__ void wtile256(const float* __restrict__ w, __hip_bfloat16* __restrict__ out,
                         int Kin, int KT, int Oin, int oblk, int u, char* LDS)
{
  int kt = u % KT;
  int yy = u / KT;
  int e = yy / oblk;
  int o0 = (yy - e * oblk) << 6;
  int k0 = kt << 6;
  float* t = (float*)LDS;  // [64][65]
  int tid = threadIdx.x;
  int tx = tid & 63, ty = tid >> 6;  // 64 x 4
#pragma unroll
  for (int i = 0; i < 16; ++i) {
    int k = k0 + ty + i * 4;
    int o = o0 + tx;
    float v = (k < Kin && o < Oin) ? w[((size_t)e * Kin + k) * Oin + o] : 0.f;
    t[(ty + i * 4) * 65 + tx] = v;
  }
  __syncthreads();
#pragma unroll
  for (int it = 0; it < 2; ++it) {
    int c = it * 256 + tid;
    int j = c & 63, sg = c >> 6;
    bf16x8 v;
#pragma unroll
    for (int e8 = 0; e8 < 8; ++e8) v[e8] = (__bf16)t[(sg * 8 + e8) * 65 + j];
    int o = o0 + j;
    int p = ((o >> 5) << 8) + (((o >> 3) & 3) << 6) + ((e >> 1) << 4) + ((o & 7) << 1) + (e & 1);
    size_t off = (((size_t)(p >> 8) * KT + kt) * 2 + (sg >> 2)) * 16384
               + (size_t)(sg & 3) * 4096 + (size_t)(p & 255) * 16;
    *(bf16x8*)((char*)out + off) = v;
  }
}

// ---- x0 staging unit: 256 chunks ----
__device__ void x0unit(int u, const float* __restrict__ cond, const float* __restrict__ lat,
                       __hip_bfloat16* __restrict__ out)
{
  int c = u * 256 + threadIdx.x;
  int RB = c / 10240;
  int r1 = c - RB * 10240;
  int T = r1 >> 11, r2 = r1 & 2047;
  int n = RB * 256 + (r2 & 255);
  int k0 = T * 64 + (r2 >> 10) * 32 + ((r2 >> 8) & 3) * 8;
  bf16x8 v;
#pragma unroll
  for (int e = 0; e < 8; ++e) {
    int k = k0 + e;
    float f = (k < 219) ? cond[(size_t)n * 219 + k]
            : (k < 283) ? lat[(size_t)n * 64 + (k - 219)] : 0.f;
    v[e] = (__bf16)f;
  }
  *(bf16x8*)((char*)out + (size_t)c * 16) = v;
}

// ---- x1 latent unit (T=8 of KT=9): 256 chunks ----
__device__ void x1lat(int u, const float* __restrict__ lat, __hip_bfloat16* __restrict__ out)
{
  int c = u * 256 + threadIdx.x;  // 0..32767
  int RB = c >> 11, r2 = c & 2047;
  int n = RB * 256 + (r2 & 255);
  int k0 = (r2 >> 10) * 32 + ((r2 >> 8) & 3) * 8;
  bf16x8 v;
#pragma unroll
  for (int e = 0; e < 8; ++e) v[e] = (__bf16)lat[(size_t)n * 64 + k0 + e];
  size_t off = ((size_t)RB * 9 + 8) * 32768 + (size_t)r2 * 16;
  *(bf16x8*)((char*)out + off) = v;
}

// ---- compact gate: 16 rows/block, ~20KB LDS, weights read from L2 ----
// Same per-output fp32 accumulation order as prior gate (k ascending, single
// scalar chain) -> bit-identical coeff.
__device__ void gate16(int gb, const float* __restrict__ phs, const float* __restrict__ lat,
                       const float* __restrict__ gw1, const float* __restrict__ gb1,
                       const float* __restrict__ gw2, const float* __restrict__ gb2,
                       const float* __restrict__ gw3, const float* __restrict__ gb3,
                       float* __restrict__ coeff, char* LDS)
{
  float* aT  = (float*)LDS;            // [128][20] f32: g0T, later h2T
  float* h1T = (float*)(LDS + 10240);  // [128][20] f32
  const int tid = threadIdx.x;
  const int n0 = gb * 16;

  for (int i = tid; i < 104 * 16; i += 256) {
    int k = i >> 4, r = i & 15;
    aT[k * 20 + r] = (k < 40) ? phs[(size_t)(n0 + r) * 40 + k]
                              : lat[(size_t)(n0 + r) * 64 + (k - 40)];
  }
  __syncthreads();

  const int col = tid & 127, rh = tid >> 7;  // rh in {0,1}: rows rh*8..rh*8+7
  // ---- layer 1: [16 x 104] x [104 x 128] ----
  {
    float acc[8] = {};
#pragma unroll 4
    for (int k = 0; k < 104; ++k) {
      float w = gw1[k * 128 + col];
#pragma unroll
      for (int r = 0; r < 8; ++r) acc[r] += aT[k * 20 + rh * 8 + r] * w;
    }
    float bb = gb1[col];
#pragma unroll
    for (int r = 0; r < 8; ++r) {
      float v = acc[r] + bb;
      h1T[col * 20 + rh * 8 + r] = v > 0.f ? v : expm1f(v);
    }
  }
  __syncthreads();
  // ---- layer 2: [16 x 128] x [128 x 128] ----
  {
    float acc[8] = {};
#pragma unroll 4
    for (int k = 0; k < 128; ++k) {
      float w = gw2[k * 128 + col];
#pragma unroll
      for (int r = 0; r < 8; ++r) acc[r] += h1T[k * 20 + rh * 8 + r] * w;
    }
    float bb = gb2[col];
#pragma unroll
    for (int r = 0; r < 8; ++r) {
      float v = acc[r] + bb;
      aT[col * 20 + rh * 8 + r] = v > 0.f ? v : expm1f(v);
    }
  }
  __syncthreads();
  // ---- layer 3 + softmax: tid<128: row=tid>>3, e=tid&7 ----
  if (tid < 128) {
    int row = tid >> 3, e = tid & 7;
    float a3 = 0.f;
    for (int k = 0; k < 128; ++k) a3 += aT[k * 20 + row] * gw3[k * 8 + e];
    float lgt = a3 + gb3[e];
    float m = lgt;
    m = fmaxf(m, __shfl_xor(m, 1));
    m = fmaxf(m, __shfl_xor(m, 2));
    m = fmaxf(m, __shfl_xor(m, 4));
    float ex = expf(lgt - m);
    float s = ex;
    s += __shfl_xor(s, 1);
    s += __shfl_xor(s, 2);
    s += __shfl_xor(s, 4);
    coeff[(size_t)(n0 + row) * 8 + e] = ex / s;
  }
}

// ---- prepG: gate (first, 256 blk) + ALL staging in one kernel ----
__global__ __launch_bounds__(256) void prepG(
    const float* __restrict__ latent, const float* __restrict__ condition,
    const float* __restrict__ phase,
    const float* __restrict__ gw1, const float* __restrict__ gb1,
    const float* __restrict__ gw2, const float* __restrict__ gb2,
    const float* __restrict__ gw3, const float* __restrict__ gb3,
    const float* __restrict__ w0, const float* __restrict__ w1, const float* __restrict__ w2,
    __hip_bfloat16* x0s, __hip_bfloat16* x1s,
    __hip_bfloat16* w0s, __hip_bfloat16* w1s, __hip_bfloat16* w2s,
    float* coeff)
{
  __shared__ __align__(16) char LDS[20608];
  int b = blockIdx.x;
  if (b < 256) {
    gate16(b, phase, latent, gw1, gb1, gw2, gb2, gw3, gb3, coeff, LDS);
    return;
  }
  b -= 256;
  if (b < 320)       wtile256(w0, w0s, 283, 5, 512, 8, b, LDS);
  else if (b < 896)  wtile256(w1, w1s, 576, 9, 512, 8, b - 320, LDS);
  else if (b < 1088) wtile256(w2, w2s, 512, 8, 171, 3, b - 896, LDS);
  else if (b < 1152) {
    int u0 = b - 1088;
    x1lat(u0, latent, x1s);
    x1lat(u0 + 64, latent, x1s);
  } else {
    x0unit(b - 1152, condition, latent, x0s);  // 640 units
  }
}

// =====================================================================
// GEMM: 128x256 tile, 48KB LDS single-buffer, 2 blocks/CU, rectangular
// per-XCD tile mapping (R13-verified). MODE 0 -> staged bf16; 1 -> fp32.
// =====================================================================
template <int KT, int KTD, int MODE, int BYPG>
__global__ __launch_bounds__(512, 4) void gemm_k(
    const __hip_bfloat16* __restrict__ Ap, const __hip_bfloat16* __restrict__ Bp,
    const float* __restrict__ coeff, const float* __restrict__ bias,
    __hip_bfloat16* __restrict__ dstS, float* __restrict__ dstF)
{
  __shared__ __align__(16) char lds[49152];   // A 16KB | B 32KB; epilogue overlays
  const int bid = blockIdx.x;
  const int xcd = bid & 7, r = bid >> 3;
  const int bx = ((xcd & 3) << 3) + (r & 7);
  const int by = (xcd >> 2) * BYPG + (r >> 3);
  const int tid = threadIdx.x;
  const int lane = tid & 63;
  const int wid = tid >> 6;
  const int wr = wid >> 2, wc = wid & 3;
  const int l15 = lane & 15, lg = lane >> 4;
  const int aHalf = (bx & 1) * 2048;

  const char* aG = (const char*)Ap + (size_t)(bx >> 1) * KT * 32768;
  const char* bG = (const char*)Bp + (size_t)by * KT * 32768;

#define STAGE(T)                                                             \
  {                                                                          \
    const char* gA_ = aG + (size_t)(T) * 32768;                              \
    const char* gB_ = bG + (size_t)(T) * 32768;                              \
    _Pragma("unroll") for (int i = 0; i < 2; ++i) {                          \
      int c = i * 512 + tid;                                                 \
      gl_lds16(gA_ + (c >> 9) * 16384 + ((c >> 7) & 3) * 4096 + aHalf        \
                   + (c & 127) * 16,                                         \
               lds + c * 16);                                                \
    }                                                                        \
    _Pragma("unroll") for (int i = 0; i < 4; ++i) {                          \
      int c = i * 512 + tid;                                                 \
      gl_lds16(gB_ + c * 16, lds + 16384 + c * 16);                          \
    }                                                                        \
  }

  f32x4 acc[4][4] = {};

  STAGE(0);
  asm volatile("s_waitcnt vmcnt(0)" ::: "memory");
  __builtin_amdgcn_s_barrier();

#pragma unroll 1
  for (int t = 0; t < KT; ++t) {
#pragma unroll
    for (int s = 0; s < 2; ++s) {
      bf16x8 a[4], b[4];
#pragma unroll
      for (int fm = 0; fm < 4; ++fm)
        a[fm] = *(const bf16x8*)(lds + s * 8192 + lg * 2048
                                 + ((wr << 6) + fm * 16 + l15) * 16);
#pragma unroll
      for (int nf = 0; nf < 4; ++nf)
        b[nf] = *(const bf16x8*)(lds + 16384 + s * 16384 + lg * 4096
                                 + (wc << 10) + nf * 256 + l15 * 16);
#pragma unroll
      for (int fm = 0; fm < 4; ++fm)
#pragma unroll
        for (int nf = 0; nf < 4; ++nf)
          acc[fm][nf] = __builtin_amdgcn_mfma_f32_16x16x32_bf16(a[fm], b[nf], acc[fm][nf], 0, 0, 0);
    }
    if (t + 1 < KT) {
      __builtin_amdgcn_s_barrier();
      STAGE(t + 1);
      asm volatile("s_waitcnt vmcnt(0)" ::: "memory");
      __builtin_amdgcn_s_barrier();
    }
  }
#undef STAGE
  __syncthreads();  // lds reuse boundary

  // ---- fused expert-blend epilogue (coeff transposed [8][132]: conflict-free) ----
  float* cl2 = (float*)lds;                  // 8 x 132 f32
  float* tb  = (float*)(lds + 4352);         // [128][33] f32 (MODE 0)
  {
#pragma unroll
    for (int i = 0; i < 2; ++i) {
      int idx = i * 512 + tid;
      int e = idx & 7, n = idx >> 3;
      cl2[e * 132 + n] = coeff[((size_t)bx * 128 + n) * 8 + e];
    }
  }
  __syncthreads();
  const int e0 = lane & 1;
  const int o_loc = (wc << 3) + (l15 >> 1);

  if (MODE == 0) {
    float bb[4];
#pragma unroll
    for (int fn = 0; fn < 4; ++fn) bb[fn] = bias[(fn * 2 + e0) * 512 + by * 32 + o_loc];
#pragma unroll
    for (int fm = 0; fm < 4; ++fm) {
#pragma unroll
      for (int r2 = 0; r2 < 4; ++r2) {
        int n_loc = (wr << 6) + fm * 16 + (lg << 2) + r2;
        float s = 0.f;
#pragma unroll
        for (int fn = 0; fn < 4; ++fn)
          s += cl2[(fn * 2 + e0) * 132 + n_loc] * (acc[fm][fn][r2] + bb[fn]);
        s += __shfl_xor(s, 1);
        s = s > 0.f ? s : expm1f(s);
        if ((lane & 1) == (fm & 1)) tb[n_loc * 33 + o_loc] = s;
      }
    }
    __syncthreads();
    {
      int n_loc = tid & 127, c = tid >> 7;
      const float* p = &tb[n_loc * 33 + c * 8];
      bf16x8 v;
#pragma unroll
      for (int j = 0; j < 8; ++j) v[j] = (__bf16)p[j];
      size_t off = (((size_t)(bx >> 1) * KTD + (by >> 1)) * 2 + (by & 1)) * 16384
                 + (size_t)c * 4096 + (size_t)((bx & 1) * 128 + n_loc) * 16;
      *(bf16x8*)((char*)dstS + off) = v;
    }
  } else {
    const int o_g = by * 32 + o_loc;
    if (o_g < 171) {
      float bb[4];
#pragma unroll
      for (int fn = 0; fn < 4; ++fn) bb[fn] = bias[(fn * 2 + e0) * 171 + o_g];
#pragma unroll
      for (int fm = 0; fm < 4; ++fm) {
#pragma unroll
        for (int r2 = 0; r2 < 4; ++r2) {
          int n_loc = (wr << 6) + fm * 16 + (lg << 2) + r2;
          float s = 0.f;
#pragma unroll
          for (int fn = 0; fn < 4; ++fn)
            s += cl2[(fn * 2 + e0) * 132 + n_loc] * (acc[fm][fn][r2] + bb[fn]);
          s += __shfl_xor(s, 1);
          if ((lane & 1) == (fm & 1))
            dstF[(size_t)(bx * 128 + n_loc) * 171 + o_g] = s;
        }
      }
    }
  }
}

// ---------------- launch ----------------
extern "C" void kernel_launch(void* const* d_in, const int* in_sizes, int n_in,
                              void* d_out, int out_size, void* d_ws, size_t ws_size,
                              hipStream_t stream)
{
  const float* latent    = (const float*)d_in[0];
  const float* condition = (const float*)d_in[1];
  const float* phase     = (const float*)d_in[2];
  const float* gw1 = (const float*)d_in[3];
  const float* gb1 = (const float*)d_in[4];
  const float* gw2 = (const float*)d_in[5];
  const float* gb2 = (const float*)d_in[6];
  const float* gw3 = (const float*)d_in[7];
  const float* gb3 = (const float*)d_in[8];
  const float* w0  = (const float*)d_in[9];
  const float* b0  = (const float*)d_in[10];
  const float* w1  = (const float*)d_in[11];
  const float* b1  = (const float*)d_in[12];
  const float* w2  = (const float*)d_in[13];
  const float* b2  = (const float*)d_in[14];

  float* out   = (float*)d_out;
  float* coeff = out + (size_t)NR * 171;

  char* ws = (char*)d_ws;
  __hip_bfloat16* x0s = (__hip_bfloat16*)ws; ws += (size_t)16 * 5 * 32768;
  __hip_bfloat16* x1s = (__hip_bfloat16*)ws; ws += (size_t)16 * 9 * 32768;
  __hip_bfloat16* x2s = (__hip_bfloat16*)ws; ws += (size_t)16 * 8 * 32768;
  __hip_bfloat16* w0s = (__hip_bfloat16*)ws; ws += (size_t)16 * 5 * 32768;
  __hip_bfloat16* w1s = (__hip_bfloat16*)ws; ws += (size_t)16 * 9 * 32768;
  __hip_bfloat16* w2s = (__hip_bfloat16*)ws; ws += (size_t)6 * 8 * 32768;

  // K1: gate (256 blocks, first) + all staging (1792 blocks) in ONE kernel
  prepG<<<2048, 256, 0, stream>>>(latent, condition, phase,
                                  gw1, gb1, gw2, gb2, gw3, gb3,
                                  w0, w1, w2,
                                  x0s, x1s, w0s, w1s, w2s, coeff);

  // K2-K4: 128x256-tile fused GEMMs, rectangular XCD-L2 tile mapping
  gemm_k<5, 9, 0, 8><<<512, 512, 0, stream>>>(x0s, w0s, coeff, b0, x1s, nullptr);
  gemm_k<9, 8, 0, 8><<<512, 512, 0, stream>>>(x1s, w1s, coeff, b1, x2s, nullptr);
  gemm_k<8, 0, 1, 3><<<192, 512, 0, stream>>>(x2s, w2s, coeff, b2, nullptr, out);
}

// Round 15
// 78.152 us; speedup vs baseline: 1.2220x; 1.0887x over previous
//
#include <hip/hip_runtime.h>
#include <hip/hip_bf16.h>

#define NR 4096

typedef float f32x4 __attribute__((ext_vector_type(4)));
typedef __bf16 bf16x8 __attribute__((ext_vector_type(8)));

typedef __attribute__((address_space(1))) unsigned int u32_g;
typedef __attribute__((address_space(3))) unsigned int u32_l;

__device__ __forceinline__ void gl_lds16(const void* g, void* l) {
  __builtin_amdgcn_global_load_lds((const u32_g*)g, (u32_l*)l, 16, 0, 0);
}

// =====================================================================
// Staged operand layout (bf16): logical Z[rows][K], row-blocks RB of 256,
// K-tiles T of 64:  chunk(row,k) at
//   off = ((RB*KT + T)*2 + s)*16384 + g*4096 + (row&255)*16 + e*2
// B cols expert-interleaved: p = (o>>5)*256+((o>>3)&3)*64+(e>>1)*16+(o&7)*2+(e&1)
//   => in-tile: e = fn*2+(l15&1), o = by*32 + wc*8 + (l15>>1)
// =====================================================================

// ---- 256-thread weight tile stage ----
__device__ void wtile256(const float* __restrict__ w, __hip_bfloat16* __restrict__ out,
                         int Kin, int KT, int Oin, int oblk, int u, char* LDS)
{
  int kt = u % KT;
  int yy = u / KT;
  int e = yy / oblk;
  int o0 = (yy - e * oblk) << 6;
  int k0 = kt << 6;
  float* t = (float*)LDS;  // [64][65]
  int tid = threadIdx.x;
  int tx = tid & 63, ty = tid >> 6;  // 64 x 4
#pragma unroll
  for (int i = 0; i < 16; ++i) {
    int k = k0 + ty + i * 4;
    int o = o0 + tx;
    float v = (k < Kin && o < Oin) ? w[((size_t)e * Kin + k) * Oin + o] : 0.f;
    t[(ty + i * 4) * 65 + tx] = v;
  }
  __syncthreads();
#pragma unroll
  for (int it = 0; it < 2; ++it) {
    int c = it * 256 + tid;
    int j = c & 63, sg = c >> 6;
    bf16x8 v;
#pragma unroll
    for (int e8 = 0; e8 < 8; ++e8) v[e8] = (__bf16)t[(sg * 8 + e8) * 65 + j];
    int o = o0 + j;
    int p = ((o >> 5) << 8) + (((o >> 3) & 3) << 6) + ((e >> 1) << 4) + ((o & 7) << 1) + (e & 1);
    size_t off = (((size_t)(p >> 8) * KT + kt) * 2 + (sg >> 2)) * 16384
               + (size_t)(sg & 3) * 4096 + (size_t)(p & 255) * 16;
    *(bf16x8*)((char*)out + off) = v;
  }
}

// ---- x0 staging unit: 256 chunks ----
__device__ void x0unit(int u, const float* __restrict__ cond, const float* __restrict__ lat,
                       __hip_bfloat16* __restrict__ out)
{
  int c = u * 256 + threadIdx.x;
  int RB = c / 10240;
  int r1 = c - RB * 10240;
  int T = r1 >> 11, r2 = r1 & 2047;
  int n = RB * 256 + (r2 & 255);
  int k0 = T * 64 + (r2 >> 10) * 32 + ((r2 >> 8) & 3) * 8;
  bf16x8 v;
#pragma unroll
  for (int e = 0; e < 8; ++e) {
    int k = k0 + e;
    float f = (k < 219) ? cond[(size_t)n * 219 + k]
            : (k < 283) ? lat[(size_t)n * 64 + (k - 219)] : 0.f;
    v[e] = (__bf16)f;
  }
  *(bf16x8*)((char*)out + (size_t)c * 16) = v;
}

// ---- x1 latent unit (T=8 of KT=9): 256 chunks ----
__device__ void x1lat(int u, const float* __restrict__ lat, __hip_bfloat16* __restrict__ out)
{
  int c = u * 256 + threadIdx.x;  // 0..32767
  int RB = c >> 11, r2 = c & 2047;
  int n = RB * 256 + (r2 & 255);
  int k0 = (r2 >> 10) * 32 + ((r2 >> 8) & 3) * 8;
  bf16x8 v;
#pragma unroll
  for (int e = 0; e < 8; ++e) v[e] = (__bf16)lat[(size_t)n * 64 + k0 + e];
  size_t off = ((size_t)RB * 9 + 8) * 32768 + (size_t)r2 * 16;
  *(bf16x8*)((char*)out + off) = v;
}

// ---- compact gate v2: 16 rows/block, ~24.6KB LDS, pipelined weight loads ----
// Same per-output fp32 accumulation order (k ascending, single scalar chain
// per acc[r]) -> bit-identical coeff. Unroll only deepens load ILP.
__device__ void gate16(int gb, const float* __restrict__ phs, const float* __restrict__ lat,
                       const float* __restrict__ gw1, const float* __restrict__ gb1,
                       const float* __restrict__ gw2, const float* __restrict__ gb2,
                       const float* __restrict__ gw3, const float* __restrict__ gb3,
                       float* __restrict__ coeff, char* LDS)
{
  float* aT  = (float*)LDS;            // [128][20] f32: g0T, later h2T (10240 B)
  float* h1T = (float*)(LDS + 10240);  // [128][20] f32
  float* w3L = (float*)(LDS + 20480);  // [128][8] f32 = 4096 B
  const int tid = threadIdx.x;
  const int n0 = gb * 16;

  for (int i = tid; i < 104 * 16; i += 256) {
    int k = i >> 4, r = i & 15;
    aT[k * 20 + r] = (k < 40) ? phs[(size_t)(n0 + r) * 40 + k]
                              : lat[(size_t)(n0 + r) * 64 + (k - 40)];
  }
  ((float4*)w3L)[tid] = ((const float4*)gw3)[tid];  // 256 float4 = 4KB exact
  __syncthreads();

  const int col = tid & 127, rh = tid >> 7;  // rh in {0,1}: rows rh*8..rh*8+7
  // ---- layer 1: [16 x 104] x [104 x 128], 8 loads in flight ----
  {
    float acc[8] = {};
#pragma unroll 8
    for (int k = 0; k < 104; ++k) {
      float w = gw1[k * 128 + col];
#pragma unroll
      for (int r = 0; r < 8; ++r) acc[r] += aT[k * 20 + rh * 8 + r] * w;
    }
    float bb = gb1[col];
#pragma unroll
    for (int r = 0; r < 8; ++r) {
      float v = acc[r] + bb;
      h1T[col * 20 + rh * 8 + r] = v > 0.f ? v : expm1f(v);
    }
  }
  __syncthreads();
  // ---- layer 2: [16 x 128] x [128 x 128], 8 loads in flight ----
  {
    float acc[8] = {};
#pragma unroll 8
    for (int k = 0; k < 128; ++k) {
      float w = gw2[k * 128 + col];
#pragma unroll
      for (int r = 0; r < 8; ++r) acc[r] += h1T[k * 20 + rh * 8 + r] * w;
    }
    float bb = gb2[col];
#pragma unroll
    for (int r = 0; r < 8; ++r) {
      float v = acc[r] + bb;
      aT[col * 20 + rh * 8 + r] = v > 0.f ? v : expm1f(v);
    }
  }
  __syncthreads();
  // ---- layer 3 + softmax: pure LDS (w3 staged) ----
  if (tid < 128) {
    int row = tid >> 3, e = tid & 7;
    float a3 = 0.f;
#pragma unroll 8
    for (int k = 0; k < 128; ++k) a3 += aT[k * 20 + row] * w3L[k * 8 + e];
    float lgt = a3 + gb3[e];
    float m = lgt;
    m = fmaxf(m, __shfl_xor(m, 1));
    m = fmaxf(m, __shfl_xor(m, 2));
    m = fmaxf(m, __shfl_xor(m, 4));
    float ex = expf(lgt - m);
    float s = ex;
    s += __shfl_xor(s, 1);
    s += __shfl_xor(s, 2);
    s += __shfl_xor(s, 4);
    coeff[(size_t)(n0 + row) * 8 + e] = ex / s;
  }
}

// ---- prepG: gate (first, 256 blk) + ALL staging in one kernel ----
__global__ __launch_bounds__(256) void prepG(
    const float* __restrict__ latent, const float* __restrict__ condition,
    const float* __restrict__ phase,
    const float* __restrict__ gw1, const float* __restrict__ gb1,
    const float* __restrict__ gw2, const float* __restrict__ gb2,
    const float* __restrict__ gw3, const float* __restrict__ gb3,
    const float* __restrict__ w0, const float* __restrict__ w1, const float* __restrict__ w2,
    __hip_bfloat16* x0s, __hip_bfloat16* x1s,
    __hip_bfloat16* w0s, __hip_bfloat16* w1s, __hip_bfloat16* w2s,
    float* coeff)
{
  __shared__ __align__(16) char LDS[24576];
  int b = blockIdx.x;
  if (b < 256) {
    gate16(b, phase, latent, gw1, gb1, gw2, gb2, gw3, gb3, coeff, LDS);
    return;
  }
  b -= 256;
  if (b < 320)       wtile256(w0, w0s, 283, 5, 512, 8, b, LDS);
  else if (b < 896)  wtile256(w1, w1s, 576, 9, 512, 8, b - 320, LDS);
  else if (b < 1088) wtile256(w2, w2s, 512, 8, 171, 3, b - 896, LDS);
  else if (b < 1152) {
    int u0 = b - 1088;
    x1lat(u0, latent, x1s);
    x1lat(u0 + 64, latent, x1s);
  } else {
    x0unit(b - 1152, condition, latent, x0s);  // 640 units
  }
}

// =====================================================================
// GEMM: 128x256 tile, 48KB LDS single-buffer, 2 blocks/CU, rectangular
// per-XCD tile mapping (R13-verified). MODE 0 -> staged bf16; 1 -> fp32.
// =====================================================================
template <int KT, int KTD, int MODE, int BYPG>
__global__ __launch_bounds__(512, 4) void gemm_k(
    const __hip_bfloat16* __restrict__ Ap, const __hip_bfloat16* __restrict__ Bp,
    const float* __restrict__ coeff, const float* __restrict__ bias,
    __hip_bfloat16* __restrict__ dstS, float* __restrict__ dstF)
{
  __shared__ __align__(16) char lds[49152];   // A 16KB | B 32KB; epilogue overlays
  const int bid = blockIdx.x;
  const int xcd = bid & 7, r = bid >> 3;
  const int bx = ((xcd & 3) << 3) + (r & 7);
  const int by = (xcd >> 2) * BYPG + (r >> 3);
  const int tid = threadIdx.x;
  const int lane = tid & 63;
  const int wid = tid >> 6;
  const int wr = wid >> 2, wc = wid & 3;
  const int l15 = lane & 15, lg = lane >> 4;
  const int aHalf = (bx & 1) * 2048;

  const char* aG = (const char*)Ap + (size_t)(bx >> 1) * KT * 32768;
  const char* bG = (const char*)Bp + (size_t)by * KT * 32768;

#define STAGE(T)                                                             \
  {                                                                          \
    const char* gA_ = aG + (size_t)(T) * 32768;                              \
    const char* gB_ = bG + (size_t)(T) * 32768;                              \
    _Pragma("unroll") for (int i = 0; i < 2; ++i) {                          \
      int c = i * 512 + tid;                                                 \
      gl_lds16(gA_ + (c >> 9) * 16384 + ((c >> 7) & 3) * 4096 + aHalf        \
                   + (c & 127) * 16,                                         \
               lds + c * 16);                                                \
    }                                                                        \
    _Pragma("unroll") for (int i = 0; i < 4; ++i) {                          \
      int c = i * 512 + tid;                                                 \
      gl_lds16(gB_ + c * 16, lds + 16384 + c * 16);                          \
    }                                                                        \
  }

  f32x4 acc[4][4] = {};

  STAGE(0);
  asm volatile("s_waitcnt vmcnt(0)" ::: "memory");
  __builtin_amdgcn_s_barrier();

#pragma unroll 1
  for (int t = 0; t < KT; ++t) {
#pragma unroll
    for (int s = 0; s < 2; ++s) {
      bf16x8 a[4], b[4];
#pragma unroll
      for (int fm = 0; fm < 4; ++fm)
        a[fm] = *(const bf16x8*)(lds + s * 8192 + lg * 2048
                                 + ((wr << 6) + fm * 16 + l15) * 16);
#pragma unroll
      for (int nf = 0; nf < 4; ++nf)
        b[nf] = *(const bf16x8*)(lds + 16384 + s * 16384 + lg * 4096
                                 + (wc << 10) + nf * 256 + l15 * 16);
#pragma unroll
      for (int fm = 0; fm < 4; ++fm)
#pragma unroll
        for (int nf = 0; nf < 4; ++nf)
          acc[fm][nf] = __builtin_amdgcn_mfma_f32_16x16x32_bf16(a[fm], b[nf], acc[fm][nf], 0, 0, 0);
    }
    if (t + 1 < KT) {
      __builtin_amdgcn_s_barrier();
      STAGE(t + 1);
      asm volatile("s_waitcnt vmcnt(0)" ::: "memory");
      __builtin_amdgcn_s_barrier();
    }
  }
#undef STAGE
  __syncthreads();  // lds reuse boundary

  // ---- fused expert-blend epilogue (coeff transposed [8][132]: conflict-free) ----
  float* cl2 = (float*)lds;                  // 8 x 132 f32
  float* tb  = (float*)(lds + 4352);         // [128][33] f32 (MODE 0)
  {
#pragma unroll
    for (int i = 0; i < 2; ++i) {
      int idx = i * 512 + tid;
      int e = idx & 7, n = idx >> 3;
      cl2[e * 132 + n] = coeff[((size_t)bx * 128 + n) * 8 + e];
    }
  }
  __syncthreads();
  const int e0 = lane & 1;
  const int o_loc = (wc << 3) + (l15 >> 1);

  if (MODE == 0) {
    float bb[4];
#pragma unroll
    for (int fn = 0; fn < 4; ++fn) bb[fn] = bias[(fn * 2 + e0) * 512 + by * 32 + o_loc];
#pragma unroll
    for (int fm = 0; fm < 4; ++fm) {
#pragma unroll
      for (int r2 = 0; r2 < 4; ++r2) {
        int n_loc = (wr << 6) + fm * 16 + (lg << 2) + r2;
        float s = 0.f;
#pragma unroll
        for (int fn = 0; fn < 4; ++fn)
          s += cl2[(fn * 2 + e0) * 132 + n_loc] * (acc[fm][fn][r2] + bb[fn]);
        s += __shfl_xor(s, 1);
        s = s > 0.f ? s : expm1f(s);
        if ((lane & 1) == (fm & 1)) tb[n_loc * 33 + o_loc] = s;
      }
    }
    __syncthreads();
    {
      int n_loc = tid & 127, c = tid >> 7;
      const float* p = &tb[n_loc * 33 + c * 8];
      bf16x8 v;
#pragma unroll
      for (int j = 0; j < 8; ++j) v[j] = (__bf16)p[j];
      size_t off = (((size_t)(bx >> 1) * KTD + (by >> 1)) * 2 + (by & 1)) * 16384
                 + (size_t)c * 4096 + (size_t)((bx & 1) * 128 + n_loc) * 16;
      *(bf16x8*)((char*)dstS + off) = v;
    }
  } else {
    const int o_g = by * 32 + o_loc;
    if (o_g < 171) {
      float bb[4];
#pragma unroll
      for (int fn = 0; fn < 4; ++fn) bb[fn] = bias[(fn * 2 + e0) * 171 + o_g];
#pragma unroll
      for (int fm = 0; fm < 4; ++fm) {
#pragma unroll
        for (int r2 = 0; r2 < 4; ++r2) {
          int n_loc = (wr << 6) + fm * 16 + (lg << 2) + r2;
          float s = 0.f;
#pragma unroll
          for (int fn = 0; fn < 4; ++fn)
            s += cl2[(fn * 2 + e0) * 132 + n_loc] * (acc[fm][fn][r2] + bb[fn]);
          s += __shfl_xor(s, 1);
          if ((lane & 1) == (fm & 1))
            dstF[(size_t)(bx * 128 + n_loc) * 171 + o_g] = s;
        }
      }
    }
  }
}

// ---------------- launch ----------------
extern "C" void kernel_launch(void* const* d_in, const int* in_sizes, int n_in,
                              void* d_out, int out_size, void* d_ws, size_t ws_size,
                              hipStream_t stream)
{
  const float* latent    = (const float*)d_in[0];
  const float* condition = (const float*)d_in[1];
  const float* phase     = (const float*)d_in[2];
  const float* gw1 = (const float*)d_in[3];
  const float* gb1 = (const float*)d_in[4];
  const float* gw2 = (const float*)d_in[5];
  const float* gb2 = (const float*)d_in[6];
  const float* gw3 = (const float*)d_in[7];
  const float* gb3 = (const float*)d_in[8];
  const float* w0  = (const float*)d_in[9];
  const float* b0  = (const float*)d_in[10];
  const float* w1  = (const float*)d_in[11];
  const float* b1  = (const float*)d_in[12];
  const float* w2  = (const float*)d_in[13];
  const float* b2  = (const float*)d_in[14];

  float* out   = (float*)d_out;
  float* coeff = out + (size_t)NR * 171;

  char* ws = (char*)d_ws;
  __hip_bfloat16* x0s = (__hip_bfloat16*)ws; ws += (size_t)16 * 5 * 32768;
  __hip_bfloat16* x1s = (__hip_bfloat16*)ws; ws += (size_t)16 * 9 * 32768;
  __hip_bfloat16* x2s = (__hip_bfloat16*)ws; ws += (size_t)16 * 8 * 32768;
  __hip_bfloat16* w0s = (__hip_bfloat16*)ws; ws += (size_t)16 * 5 * 32768;
  __hip_bfloat16* w1s = (__hip_bfloat16*)ws; ws += (size_t)16 * 9 * 32768;
  __hip_bfloat16* w2s = (__hip_bfloat16*)ws; ws += (size_t)6 * 8 * 32768;

  // K1: gate (256 blocks, first) + all staging (1792 blocks) in ONE kernel
  prepG<<<2048, 256, 0, stream>>>(latent, condition, phase,
                                  gw1, gb1, gw2, gb2, gw3, gb3,
                                  w0, w1, w2,
                                  x0s, x1s, w0s, w1s, w2s, coeff);

  // K2-K4: 128x256-tile fused GEMMs, rectangular XCD-L2 tile mapping
  gemm_k<5, 9, 0, 8><<<512, 512, 0, stream>>>(x0s, w0s, coeff, b0, x1s, nullptr);
  gemm_k<9, 8, 0, 8><<<512, 512, 0, stream>>>(x1s, w1s, coeff, b1, x2s, nullptr);
  gemm_k<8, 0, 1, 3><<<192, 512, 0, stream>>>(x2s, w2s, coeff, b2, nullptr, out);
}

// Round 16
// 74.973 us; speedup vs baseline: 1.2738x; 1.0424x over previous
//
#include <hip/hip_runtime.h>
#include <hip/hip_bf16.h>

#define NR 4096

typedef float f32x4 __attribute__((ext_vector_type(4)));
typedef __bf16 bf16x8 __attribute__((ext_vector_type(8)));

typedef __attribute__((address_space(1))) unsigned int u32_g;
typedef __attribute__((address_space(3))) unsigned int u32_l;

__device__ __forceinline__ void gl_lds16(const void* g, void* l) {
  __builtin_amdgcn_global_load_lds((const u32_g*)g, (u32_l*)l, 16, 0, 0);
}

// =====================================================================
// Staged operand layout (bf16): logical Z[rows][K], row-blocks RB of 256,
// K-tiles T of 64:  chunk(row,k) at
//   off = ((RB*KT + T)*2 + s)*16384 + g*4096 + (row&255)*16 + e*2
// B cols expert-interleaved: p = (o>>5)*256+((o>>3)&3)*64+(e>>1)*16+(o&7)*2+(e&1)
//   => in-tile: e = fn*2+(l15&1), o = by*32 + wc*8 + (l15>>1)
// =====================================================================

// ---- w-stager v2: block = (ob,T,s) = 8 experts x 32 cols x 32 k ----
// Loads coalesced (float4 rows), stores 4x4KB CONTIGUOUS (fixes the
// scattered-16B store pattern that dominated all prior stagers).
__device__ void wstage32(const float* __restrict__ w, __hip_bfloat16* __restrict__ out,
                         int Kin, int KT, int Oin, int u, char* LDS)
{
  int ob = u / (KT * 2);
  int rem = u - ob * (KT * 2);
  int T = rem >> 1, s = rem & 1;
  float* t = (float*)LDS;                    // [256][33]: row = e*32+kk, col = oo
  const int tid = threadIdx.x;
  const int kbase = T * 64 + s * 32;

  if (Oin == 512) {                          // aligned fast path (w0, w1)
#pragma unroll
    for (int i = 0; i < 8; ++i) {
      int idx = i * 256 + tid;               // 2048 float4 = 32KB
      int row = idx >> 3, c4 = idx & 7;
      int e = row >> 5, kk = row & 31;
      int k = kbase + kk;
      float4 v = {0.f, 0.f, 0.f, 0.f};
      if (k < Kin) v = *(const float4*)&w[((size_t)e * Kin + k) * 512 + ob * 32 + c4 * 4];
      t[row * 33 + c4 * 4 + 0] = v.x;
      t[row * 33 + c4 * 4 + 1] = v.y;
      t[row * 33 + c4 * 4 + 2] = v.z;
      t[row * 33 + c4 * 4 + 3] = v.w;
    }
  } else {                                   // w2: Oin=171, unaligned rows
#pragma unroll
    for (int i = 0; i < 8; ++i) {
      int idx = i * 256 + tid;
      int row = idx >> 3, c4 = idx & 7;
      int e = row >> 5, kk = row & 31;
      int k = kbase + kk;
#pragma unroll
      for (int j = 0; j < 4; ++j) {
        int o = ob * 32 + c4 * 4 + j;
        float f = (k < Kin && o < Oin) ? w[((size_t)e * Kin + k) * (size_t)Oin + o] : 0.f;
        t[row * 33 + c4 * 4 + j] = f;
      }
    }
  }
  __syncthreads();
  {
    int p = tid;                              // p = staged col within 256-block
    int e = ((p >> 4) & 3) * 2 + (p & 1);
    int oo = ((p >> 6) & 3) * 8 + ((p >> 1) & 7);
    size_t segbase = (((size_t)ob * KT + T) * 2 + s) * 16384;
#pragma unroll
    for (int g = 0; g < 4; ++g) {
      bf16x8 v;
#pragma unroll
      for (int e8 = 0; e8 < 8; ++e8) v[e8] = (__bf16)t[(e * 32 + g * 8 + e8) * 33 + oo];
      *(bf16x8*)((char*)out + segbase + g * 4096 + (size_t)p * 16) = v;
    }
  }
  __syncthreads();
}

// ---- x0 staging unit: 256 chunks ----
__device__ void x0unit(int u, const float* __restrict__ cond, const float* __restrict__ lat,
                       __hip_bfloat16* __restrict__ out)
{
  int c = u * 256 + threadIdx.x;
  int RB = c / 10240;
  int r1 = c - RB * 10240;
  int T = r1 >> 11, r2 = r1 & 2047;
  int n = RB * 256 + (r2 & 255);
  int k0 = T * 64 + (r2 >> 10) * 32 + ((r2 >> 8) & 3) * 8;
  bf16x8 v;
#pragma unroll
  for (int e = 0; e < 8; ++e) {
    int k = k0 + e;
    float f = (k < 219) ? cond[(size_t)n * 219 + k]
            : (k < 283) ? lat[(size_t)n * 64 + (k - 219)] : 0.f;
    v[e] = (__bf16)f;
  }
  *(bf16x8*)((char*)out + (size_t)c * 16) = v;
}

// ---- x1 latent unit (T=8 of KT=9): 256 chunks ----
__device__ void x1lat(int u, const float* __restrict__ lat, __hip_bfloat16* __restrict__ out)
{
  int c = u * 256 + threadIdx.x;  // 0..32767
  int RB = c >> 11, r2 = c & 2047;
  int n = RB * 256 + (r2 & 255);
  int k0 = (r2 >> 10) * 32 + ((r2 >> 8) & 3) * 8;
  bf16x8 v;
#pragma unroll
  for (int e = 0; e < 8; ++e) v[e] = (__bf16)lat[(size_t)n * 64 + k0 + e];
  size_t off = ((size_t)RB * 9 + 8) * 32768 + (size_t)r2 * 16;
  *(bf16x8*)((char*)out + off) = v;
}

// ---- compact gate: 16 rows/block, pipelined weight loads (R15-verified) ----
__device__ void gate16(int gb, const float* __restrict__ phs, const float* __restrict__ lat,
                       const float* __restrict__ gw1, const float* __restrict__ gb1,
                       const float* __restrict__ gw2, const float* __restrict__ gb2,
                       const float* __restrict__ gw3, const float* __restrict__ gb3,
                       float* __restrict__ coeff, char* LDS)
{
  float* aT  = (float*)LDS;            // [128][20] f32: g0T, later h2T
  float* h1T = (float*)(LDS + 10240);  // [128][20] f32
  float* w3L = (float*)(LDS + 20480);  // [128][8] f32
  const int tid = threadIdx.x;
  const int n0 = gb * 16;

  for (int i = tid; i < 104 * 16; i += 256) {
    int k = i >> 4, r = i & 15;
    aT[k * 20 + r] = (k < 40) ? phs[(size_t)(n0 + r) * 40 + k]
                              : lat[(size_t)(n0 + r) * 64 + (k - 40)];
  }
  ((float4*)w3L)[tid] = ((const float4*)gw3)[tid];
  __syncthreads();

  const int col = tid & 127, rh = tid >> 7;
  {
    float acc[8] = {};
#pragma unroll 8
    for (int k = 0; k < 104; ++k) {
      float w = gw1[k * 128 + col];
#pragma unroll
      for (int r = 0; r < 8; ++r) acc[r] += aT[k * 20 + rh * 8 + r] * w;
    }
    float bb = gb1[col];
#pragma unroll
    for (int r = 0; r < 8; ++r) {
      float v = acc[r] + bb;
      h1T[col * 20 + rh * 8 + r] = v > 0.f ? v : expm1f(v);
    }
  }
  __syncthreads();
  {
    float acc[8] = {};
#pragma unroll 8
    for (int k = 0; k < 128; ++k) {
      float w = gw2[k * 128 + col];
#pragma unroll
      for (int r = 0; r < 8; ++r) acc[r] += h1T[k * 20 + rh * 8 + r] * w;
    }
    float bb = gb2[col];
#pragma unroll
    for (int r = 0; r < 8; ++r) {
      float v = acc[r] + bb;
      aT[col * 20 + rh * 8 + r] = v > 0.f ? v : expm1f(v);
    }
  }
  __syncthreads();
  if (tid < 128) {
    int row = tid >> 3, e = tid & 7;
    float a3 = 0.f;
#pragma unroll 8
    for (int k = 0; k < 128; ++k) a3 += aT[k * 20 + row] * w3L[k * 8 + e];
    float lgt = a3 + gb3[e];
    float m = lgt;
    m = fmaxf(m, __shfl_xor(m, 1));
    m = fmaxf(m, __shfl_xor(m, 2));
    m = fmaxf(m, __shfl_xor(m, 4));
    float ex = expf(lgt - m);
    float s = ex;
    s += __shfl_xor(s, 1);
    s += __shfl_xor(s, 2);
    s += __shfl_xor(s, 4);
    coeff[(size_t)(n0 + row) * 8 + e] = ex / s;
  }
}

// ---- prepG: gate (first) + coalesced w-stagers + x staging, one kernel ----
__global__ __launch_bounds__(256) void prepG(
    const float* __restrict__ latent, const float* __restrict__ condition,
    const float* __restrict__ phase,
    const float* __restrict__ gw1, const float* __restrict__ gb1,
    const float* __restrict__ gw2, const float* __restrict__ gb2,
    const float* __restrict__ gw3, const float* __restrict__ gb3,
    const float* __restrict__ w0, const float* __restrict__ w1, const float* __restrict__ w2,
    __hip_bfloat16* x0s, __hip_bfloat16* x1s,
    __hip_bfloat16* w0s, __hip_bfloat16* w1s, __hip_bfloat16* w2s,
    float* coeff)
{
  __shared__ __align__(16) char LDS[33792];   // max(gate 24.6K, wstage [256][33] f32)
  int b = blockIdx.x;
  if (b < 256) {
    gate16(b, phase, latent, gw1, gb1, gw2, gb2, gw3, gb3, coeff, LDS);
    return;
  }
  b -= 256;
  if (b < 288)       wstage32(w1, w1s, 576, 9, 512, b, LDS);        // 288 blocks
  else if (b < 448)  wstage32(w0, w0s, 283, 5, 512, b - 288, LDS);  // 160
  else if (b < 544)  wstage32(w2, w2s, 512, 8, 171, b - 448, LDS);  // 96
  else if (b < 1184) x0unit(b - 544, condition, latent, x0s);       // 640 units
  else {
    int u0 = (b - 1184) * 2;
    x1lat(u0, latent, x1s);
    x1lat(u0 + 1, latent, x1s);                                     // 64 blocks
  }
}

// =====================================================================
// GEMM: 128x256 tile, 48KB LDS single-buffer, 2 blocks/CU, rectangular
// per-XCD tile mapping (R13-verified). MODE 0 -> staged bf16; 1 -> fp32.
// =====================================================================
template <int KT, int KTD, int MODE, int BYPG>
__global__ __launch_bounds__(512, 4) void gemm_k(
    const __hip_bfloat16* __restrict__ Ap, const __hip_bfloat16* __restrict__ Bp,
    const float* __restrict__ coeff, const float* __restrict__ bias,
    __hip_bfloat16* __restrict__ dstS, float* __restrict__ dstF)
{
  __shared__ __align__(16) char lds[49152];   // A 16KB | B 32KB; epilogue overlays
  const int bid = blockIdx.x;
  const int xcd = bid & 7, r = bid >> 3;
  const int bx = ((xcd & 3) << 3) + (r & 7);
  const int by = (xcd >> 2) * BYPG + (r >> 3);
  const int tid = threadIdx.x;
  const int lane = tid & 63;
  const int wid = tid >> 6;
  const int wr = wid >> 2, wc = wid & 3;
  const int l15 = lane & 15, lg = lane >> 4;
  const int aHalf = (bx & 1) * 2048;

  const char* aG = (const char*)Ap + (size_t)(bx >> 1) * KT * 32768;
  const char* bG = (const char*)Bp + (size_t)by * KT * 32768;

#define STAGE(T)                                                             \
  {                                                                          \
    const char* gA_ = aG + (size_t)(T) * 32768;                              \
    const char* gB_ = bG + (size_t)(T) * 32768;                              \
    _Pragma("unroll") for (int i = 0; i < 2; ++i) {                          \
      int c = i * 512 + tid;                                                 \
      gl_lds16(gA_ + (c >> 9) * 16384 + ((c >> 7) & 3) * 4096 + aHalf        \
                   + (c & 127) * 16,                                         \
               lds + c * 16);                                                \
    }                                                                        \
    _Pragma("unroll") for (int i = 0; i < 4; ++i) {                          \
      int c = i * 512 + tid;                                                 \
      gl_lds16(gB_ + c * 16, lds + 16384 + c * 16);                          \
    }                                                                        \
  }

  f32x4 acc[4][4] = {};

  STAGE(0);
  asm volatile("s_waitcnt vmcnt(0)" ::: "memory");
  __builtin_amdgcn_s_barrier();

#pragma unroll 1
  for (int t = 0; t < KT; ++t) {
#pragma unroll
    for (int s = 0; s < 2; ++s) {
      bf16x8 a[4], b[4];
#pragma unroll
      for (int fm = 0; fm < 4; ++fm)
        a[fm] = *(const bf16x8*)(lds + s * 8192 + lg * 2048
                                 + ((wr << 6) + fm * 16 + l15) * 16);
#pragma unroll
      for (int nf = 0; nf < 4; ++nf)
        b[nf] = *(const bf16x8*)(lds + 16384 + s * 16384 + lg * 4096
                                 + (wc << 10) + nf * 256 + l15 * 16);
#pragma unroll
      for (int fm = 0; fm < 4; ++fm)
#pragma unroll
        for (int nf = 0; nf < 4; ++nf)
          acc[fm][nf] = __builtin_amdgcn_mfma_f32_16x16x32_bf16(a[fm], b[nf], acc[fm][nf], 0, 0, 0);
    }
    if (t + 1 < KT) {
      __builtin_amdgcn_s_barrier();
      STAGE(t + 1);
      asm volatile("s_waitcnt vmcnt(0)" ::: "memory");
      __builtin_amdgcn_s_barrier();
    }
  }
#undef STAGE
  __syncthreads();  // lds reuse boundary

  // ---- fused expert-blend epilogue (coeff transposed [8][132]: conflict-free) ----
  float* cl2 = (float*)lds;                  // 8 x 132 f32
  float* tb  = (float*)(lds + 4352);         // [128][33] f32 (MODE 0)
  {
#pragma unroll
    for (int i = 0; i < 2; ++i) {
      int idx = i * 512 + tid;
      int e = idx & 7, n = idx >> 3;
      cl2[e * 132 + n] = coeff[((size_t)bx * 128 + n) * 8 + e];
    }
  }
  __syncthreads();
  const int e0 = lane & 1;
  const int o_loc = (wc << 3) + (l15 >> 1);

  if (MODE == 0) {
    float bb[4];
#pragma unroll
    for (int fn = 0; fn < 4; ++fn) bb[fn] = bias[(fn * 2 + e0) * 512 + by * 32 + o_loc];
#pragma unroll
    for (int fm = 0; fm < 4; ++fm) {
#pragma unroll
      for (int r2 = 0; r2 < 4; ++r2) {
        int n_loc = (wr << 6) + fm * 16 + (lg << 2) + r2;
        float s = 0.f;
#pragma unroll
        for (int fn = 0; fn < 4; ++fn)
          s += cl2[(fn * 2 + e0) * 132 + n_loc] * (acc[fm][fn][r2] + bb[fn]);
        s += __shfl_xor(s, 1);
        s = s > 0.f ? s : expm1f(s);
        if ((lane & 1) == (fm & 1)) tb[n_loc * 33 + o_loc] = s;
      }
    }
    __syncthreads();
    {
      int n_loc = tid & 127, c = tid >> 7;
      const float* p = &tb[n_loc * 33 + c * 8];
      bf16x8 v;
#pragma unroll
      for (int j = 0; j < 8; ++j) v[j] = (__bf16)p[j];
      size_t off = (((size_t)(bx >> 1) * KTD + (by >> 1)) * 2 + (by & 1)) * 16384
                 + (size_t)c * 4096 + (size_t)((bx & 1) * 128 + n_loc) * 16;
      *(bf16x8*)((char*)dstS + off) = v;
    }
  } else {
    const int o_g = by * 32 + o_loc;
    if (o_g < 171) {
      float bb[4];
#pragma unroll
      for (int fn = 0; fn < 4; ++fn) bb[fn] = bias[(fn * 2 + e0) * 171 + o_g];
#pragma unroll
      for (int fm = 0; fm < 4; ++fm) {
#pragma unroll
        for (int r2 = 0; r2 < 4; ++r2) {
          int n_loc = (wr << 6) + fm * 16 + (lg << 2) + r2;
          float s = 0.f;
#pragma unroll
          for (int fn = 0; fn < 4; ++fn)
            s += cl2[(fn * 2 + e0) * 132 + n_loc] * (acc[fm][fn][r2] + bb[fn]);
          s += __shfl_xor(s, 1);
          if ((lane & 1) == (fm & 1))
            dstF[(size_t)(bx * 128 + n_loc) * 171 + o_g] = s;
        }
      }
    }
  }
}

// ---------------- launch ----------------
extern "C" void kernel_launch(void* const* d_in, const int* in_sizes, int n_in,
                              void* d_out, int out_size, void* d_ws, size_t ws_size,
                              hipStream_t stream)
{
  const float* latent    = (const float*)d_in[0];
  const float* condition = (const float*)d_in[1];
  const float* phase     = (const float*)d_in[2];
  const float* gw1 = (const float*)d_in[3];
  const float* gb1 = (const float*)d_in[4];
  const float* gw2 = (const float*)d_in[5];
  const float* gb2 = (const float*)d_in[6];
  const float* gw3 = (const float*)d_in[7];
  const float* gb3 = (const float*)d_in[8];
  const float* w0  = (const float*)d_in[9];
  const float* b0  = (const float*)d_in[10];
  const float* w1  = (const float*)d_in[11];
  const float* b1  = (const float*)d_in[12];
  const float* w2  = (const float*)d_in[13];
  const float* b2  = (const float*)d_in[14];

  float* out   = (float*)d_out;
  float* coeff = out + (size_t)NR * 171;

  char* ws = (char*)d_ws;
  __hip_bfloat16* x0s = (__hip_bfloat16*)ws; ws += (size_t)16 * 5 * 32768;
  __hip_bfloat16* x1s = (__hip_bfloat16*)ws; ws += (size_t)16 * 9 * 32768;
  __hip_bfloat16* x2s = (__hip_bfloat16*)ws; ws += (size_t)16 * 8 * 32768;
  __hip_bfloat16* w0s = (__hip_bfloat16*)ws; ws += (size_t)16 * 5 * 32768;
  __hip_bfloat16* w1s = (__hip_bfloat16*)ws; ws += (size_t)16 * 9 * 32768;
  __hip_bfloat16* w2s = (__hip_bfloat16*)ws; ws += (size_t)6 * 8 * 32768;

  // K1: gate (256, first) + w1/w0/w2 coalesced stagers (544) + x0 (640) + x1 (64)
  prepG<<<1504, 256, 0, stream>>>(latent, condition, phase,
                                  gw1, gb1, gw2, gb2, gw3, gb3,
                                  w0, w1, w2,
                                  x0s, x1s, w0s, w1s, w2s, coeff);

  // K2-K4: 128x256-tile fused GEMMs, rectangular XCD-L2 tile mapping
  gemm_k<5, 9, 0, 8><<<512, 512, 0, stream>>>(x0s, w0s, coeff, b0, x1s, nullptr);
  gemm_k<9, 8, 0, 8><<<512, 512, 0, stream>>>(x1s, w1s, coeff, b1, x2s, nullptr);
  gemm_k<8, 0, 1, 3><<<192, 512, 0, stream>>>(x2s, w2s, coeff, b2, nullptr, out);
}